// Round 3
// baseline (84.127 us; speedup 1.0000x reference)
//
#include <hip/hip_runtime.h>
#include <math.h>

#define B_ROWS 4096
#define LBL 100
#define NCT 32     // 32x32 tile grid, upper triangle only
#define NTRI 528   // 32*33/2 blocks

typedef __attribute__((ext_vector_type(8))) short bf16x8;
typedef __attribute__((ext_vector_type(4))) float f32x4;

__device__ __forceinline__ unsigned f2bf(float x) {
  union { float f; unsigned u; } a; a.f = x;
  unsigned r = a.u + 0x7fffu + ((a.u >> 16) & 1u);  // RNE
  return r >> 16;
}
__device__ __forceinline__ float bf2f(unsigned h) {
  return __uint_as_float(h << 16);
}

// Fused prep: one wave per row. Writes cf (bf16 view0, XOR-swizzled chunks:
// chunk(r,kc) of tile t at cf[t*2048 + kc*128 + ((r&127)^kc)]), 128-bit label
// masks, row sums, seedRaw = sum(bf16(f)^2) - 0.15 (lower bound on the raw
// diag MFMA dot; single source -> bit-identical for all consumers).
// Also zeroes rowAcc (its own row) and the finalize counter.
__global__ void prep_kernel(const float* __restrict__ feat,
                            const float* __restrict__ labels,
                            uint4* __restrict__ cf,
                            uint4* __restrict__ Lb,
                            int* __restrict__ rsv,
                            float* __restrict__ seedRaw,
                            float2* __restrict__ rowAcc,
                            unsigned* __restrict__ counter) {
  if (blockIdx.x == 0 && threadIdx.x == 0) *counter = 0u;
  int w = blockIdx.x * 4 + (threadIdx.x >> 6);
  int lane = threadIdx.x & 63;
  float2 f = ((const float2*)(feat + (size_t)w * 256))[lane];  // view0 row
  unsigned u0 = f2bf(f.x), u1 = f2bf(f.y);
  unsigned myu = u0 | (u1 << 16);
  float b0 = bf2f(u0), b1 = bf2f(u1);
  float s = b0 * b0 + b1 * b1;
  #pragma unroll
  for (int o = 32; o >= 1; o >>= 1) s += __shfl_xor(s, o);
  float x0 = labels[(size_t)w * LBL + lane];
  float x1 = (lane < LBL - 64) ? labels[(size_t)w * LBL + 64 + lane] : 0.0f;
  unsigned long long m0 = __ballot(x0 != 0.0f);
  unsigned long long m1 = __ballot(x1 != 0.0f);
  // pack: lane kc<16 gathers its chunk's 4 dwords from lanes kc*4+j
  int kc = lane & 15;
  unsigned q0 = __shfl(myu, kc * 4 + 0);
  unsigned q1 = __shfl(myu, kc * 4 + 1);
  unsigned q2 = __shfl(myu, kc * 4 + 2);
  unsigned q3 = __shfl(myu, kc * 4 + 3);
  if (lane < 16)
    cf[(size_t)(w >> 7) * 2048 + kc * 128 + ((w & 127) ^ kc)] =
        make_uint4(q0, q1, q2, q3);
  if (lane == 0) {
    Lb[w] = make_uint4((unsigned)m0, (unsigned)(m0 >> 32),
                       (unsigned)m1, (unsigned)(m1 >> 32));
    rsv[w] = __popcll(m0) + __popcll(m1);
    seedRaw[w] = s - 0.15f;  // 0.15 raw = 2.1 logit slack >> 1e-3 reassoc err
    rowAcc[w] = make_float2(0.0f, 0.0f);
  }
}

// One upper-triangle 128x128 tile per block — no LDS in the hot path, no
// barriers until the finalize tail. MFMA A/B fragments load directly from the
// pre-swizzled cf (per quad: 16 lanes -> one 256B segment, coalesced),
// double-buffered in regs across the 4 K-steps. Raw dots; *invT in epilogue.
// logits_max cancels in -log(p/(p+n)); terms below ref-6.3 raw underflow to 0
// in the reference's fp32 sums too. Partials are SPARSE (only diag tiles +
// rare near-threshold off-diag tiles fire): atomicAdd nonzero partials into
// rowAcc[4096] (device-coherent-point RMWs), then the last block finalizes.
// ORDERING WITHOUT FENCES: atomic RMWs are performed at the coherent point;
// a wave-local s_waitcnt vmcnt(0) (completion == performed) + __syncthreads
// before the counter RMW gives release-like ordering with NO buffer_wbl2.
// __launch_bounds__(256, 1): register demand is ~170 VGPRs (acc 64 + dbuf
// fragments 64 + epilogue state); the default cap of 128 forced ~40 regs of
// scratch spill per thread — the ~25 us of all-pipes-idle stall seen in the
// counters. min-waves=1 lifts the cap to 512; expect ~192-256 alloc, 0 spill.
__launch_bounds__(256, 1)
__global__ void main_kernel(const uint4* __restrict__ cf,
                            const uint4* __restrict__ Lb,
                            const int* __restrict__ rsv,
                            const float* __restrict__ seedRaw,
                            float2* __restrict__ rowAcc,
                            unsigned* __restrict__ counter,
                            float* __restrict__ out) {
  __shared__ unsigned s_done;
  __shared__ float s_p[4], s_c[4];

  // triangular decode: bid -> (bx, by), bx <= by
  int bid = blockIdx.x;
  int bx = 0, off = 0;
  while (bid >= off + (NCT - bx)) { off += NCT - bx; ++bx; }
  int by = bx + (bid - off);
  const bool diag = (bx == by);

  const int tid = threadIdx.x;
  const int lane = tid & 63;
  const int l15 = lane & 15;
  const int quad = lane >> 4;
  const int wave = tid >> 6;
  const int wi = (wave & 1) * 64;   // wave row offset in 128
  const int wj = (wave >> 1) * 64;  // wave col offset in 128
  const int rowBase = bx * 128;
  const int colBase = by * 128;
  const float invT = 1.0f / 0.07f;

  const uint4* Ab = cf + (size_t)bx * 2048;
  const uint4* Bb = cf + (size_t)by * 2048;

  f32x4 acc[4][4];
  #pragma unroll
  for (int ti = 0; ti < 4; ++ti)
    #pragma unroll
    for (int tj = 0; tj < 4; ++tj)
      acc[ti][tj] = (f32x4){0.f, 0.f, 0.f, 0.f};

  // K loop, register double-buffered fragment loads straight from global
  bf16x8 af[4], bfr[4], af2[4], bfr2[4];
  {
    const int kc = quad;
    #pragma unroll
    for (int t = 0; t < 4; ++t) {
      af[t]  = *(const bf16x8*)&Ab[kc * 128 + ((wi + t * 16 + l15) ^ kc)];
      bfr[t] = *(const bf16x8*)&Bb[kc * 128 + ((wj + t * 16 + l15) ^ kc)];
    }
  }
  #pragma unroll
  for (int ks = 0; ks < 4; ++ks) {
    if (ks < 3) {
      const int kc = (ks + 1) * 4 + quad;
      #pragma unroll
      for (int t = 0; t < 4; ++t) {
        af2[t]  = *(const bf16x8*)&Ab[kc * 128 + ((wi + t * 16 + l15) ^ kc)];
        bfr2[t] = *(const bf16x8*)&Bb[kc * 128 + ((wj + t * 16 + l15) ^ kc)];
      }
    }
    #pragma unroll
    for (int ti = 0; ti < 4; ++ti)
      #pragma unroll
      for (int tj = 0; tj < 4; ++tj)
        acc[ti][tj] = __builtin_amdgcn_mfma_f32_16x16x32_bf16(
            af[ti], bfr[tj], acc[ti][tj], 0, 0, 0);
    if (ks < 3) {
      #pragma unroll
      for (int t = 0; t < 4; ++t) { af[t] = af2[t]; bfr[t] = bfr2[t]; }
    }
  }

  // per-wave metadata (coalesced; one latency, L2-hot)
  uint4 clb[4];
  int crs[4];
  float scol[4], srow[16];
  #pragma unroll
  for (int tj = 0; tj < 4; ++tj) {
    int gcol = colBase + wj + tj * 16 + l15;
    clb[tj] = Lb[gcol];
    crs[tj] = rsv[gcol];
    scol[tj] = seedRaw[gcol];
  }
  #pragma unroll
  for (int ti = 0; ti < 4; ++ti) {
    float4 s4 = *(const float4*)&seedRaw[rowBase + wi + ti * 16 + quad * 4];
    srow[ti * 4 + 0] = s4.x; srow[ti * 4 + 1] = s4.y;
    srow[ti * 4 + 2] = s4.z; srow[ti * 4 + 3] = s4.w;
  }

  // epilogue: C[row][col], row=wi+ti*16+quad*4+r, col=wj+tj*16+l15 (raw dots)
  float p_s[16], n_s[16], cp[4], cn[4], cmax[4];
  #pragma unroll
  for (int i = 0; i < 16; ++i) { p_s[i] = 0.f; n_s[i] = 0.f; }
  #pragma unroll
  for (int tj = 0; tj < 4; ++tj) { cp[tj] = 0.f; cn[tj] = 0.f; cmax[tj] = -1e30f; }

  #pragma unroll
  for (int ti = 0; ti < 4; ++ti)
    #pragma unroll
    for (int r = 0; r < 4; ++r) {
      int si = ti * 4 + r;
      float l0 = acc[ti][0][r], l1 = acc[ti][1][r];
      float l2 = acc[ti][2][r], l3 = acc[ti][3][r];
      cmax[0] = fmaxf(cmax[0], l0);
      cmax[1] = fmaxf(cmax[1], l1);
      cmax[2] = fmaxf(cmax[2], l2);
      cmax[3] = fmaxf(cmax[3], l3);
      float tm = fmaxf(fmaxf(l0, l1), fmaxf(l2, l3));
      if (tm > srow[si] - 6.3f) {  // row-side slow path (~diag tiles only)
        int grow = rowBase + wi + ti * 16 + quad * 4 + r;
        uint4 la = Lb[grow];     // scattered but rare + L2-hot
        int ra = rsv[grow];
        float p = p_s[si], n = n_s[si];
        float lv[4] = {l0, l1, l2, l3};
        #pragma unroll
        for (int tj = 0; tj < 4; ++tj) {
          float e = __expf((lv[tj] - srow[si]) * invT);
          int inter = __popc(la.x & clb[tj].x) + __popc(la.y & clb[tj].y) +
                      __popc(la.z & clb[tj].z) + __popc(la.w & clb[tj].w);
          if (3 * inter > ra + crs[tj]) p += e; else n += e;  // sim>=0.5 exact
        }
        p_s[si] = p;
        n_s[si] = n;
      }
    }

  // col-side (transpose contribution) — off-diagonal tiles only, ~never fires
  if (!diag) {
    #pragma unroll
    for (int tj = 0; tj < 4; ++tj) {
      if (cmax[tj] > scol[tj] - 6.3f) {
        float p = cp[tj], n = cn[tj];
        #pragma unroll
        for (int ti = 0; ti < 4; ++ti)
          #pragma unroll
          for (int r = 0; r < 4; ++r) {
            float e = __expf((acc[ti][tj][r] - scol[tj]) * invT);
            int grow = rowBase + wi + ti * 16 + quad * 4 + r;
            uint4 la = Lb[grow];
            int inter = __popc(la.x & clb[tj].x) + __popc(la.y & clb[tj].y) +
                        __popc(la.z & clb[tj].z) + __popc(la.w & clb[tj].w);
            if (3 * inter > rsv[grow] + crs[tj]) p += e; else n += e;
          }
        cp[tj] = p;
        cn[tj] = n;
      }
    }
  }

  // row-side: sum across the 16 lanes (same quad) sharing each row; lane 0 of
  // each quad owns the row -> one float2-worth of atomics, SKIPPED when zero
  // (only diag tiles + rare off-diag near-threshold tiles ever fire).
  #pragma unroll
  for (int si = 0; si < 16; ++si) {
    float p = p_s[si], n = n_s[si];
    #pragma unroll
    for (int o = 8; o >= 1; o >>= 1) {
      p += __shfl_xor(p, o);
      n += __shfl_xor(n, o);
    }
    p_s[si] = p;
    n_s[si] = n;
  }
  if (l15 == 0) {
    #pragma unroll
    for (int ti = 0; ti < 4; ++ti)
      #pragma unroll
      for (int r = 0; r < 4; ++r) {
        float p = p_s[ti * 4 + r], n = n_s[ti * 4 + r];
        if (p != 0.f || n != 0.f) {
          int row = rowBase + wi + ti * 16 + quad * 4 + r;
          atomicAdd(&rowAcc[row].x, p);
          atomicAdd(&rowAcc[row].y, n);
        }
      }
  }
  // col-side: sum across the 4 quads sharing each column; per-lane atomics,
  // skipped when zero (almost always)
  #pragma unroll
  for (int tj = 0; tj < 4; ++tj) {
    float p = cp[tj], n = cn[tj];
    p += __shfl_xor(p, 16); n += __shfl_xor(n, 16);
    p += __shfl_xor(p, 32); n += __shfl_xor(n, 32);
    cp[tj] = p;
    cn[tj] = n;
  }
  if (!diag && quad == 0) {
    #pragma unroll
    for (int tj = 0; tj < 4; ++tj) {
      if (cp[tj] != 0.f || cn[tj] != 0.f) {
        int col = colBase + wj + tj * 16 + l15;
        atomicAdd(&rowAcc[col].x, cp[tj]);
        atomicAdd(&rowAcc[col].y, cn[tj]);
      }
    }
  }

  // finalize tail — NO __threadfence (no L2 writeback). Drain this wave's
  // outstanding coherent-point RMWs, barrier so all 4 waves are drained,
  // then one counter RMW. Completion of an atomic == performed device-wide.
  asm volatile("s_waitcnt vmcnt(0)" ::: "memory");
  __syncthreads();
  if (tid == 0) s_done = atomicAdd(counter, 1u);
  __syncthreads();
  if (s_done == NTRI - 1) {  // last block: all rowAcc adds are globally done
    float per = 0.f, cnt = 0.f;
    #pragma unroll
    for (int it = 0; it < B_ROWS / 256; ++it) {
      int row = it * 256 + tid;
      unsigned long long u = __hip_atomic_load(
          (const unsigned long long*)&rowAcc[row], __ATOMIC_RELAXED,
          __HIP_MEMORY_SCOPE_AGENT);           // cache-bypassing coherent read
      float p = __uint_as_float((unsigned)u);
      float n = __uint_as_float((unsigned)(u >> 32));
      if (rsv[row] > 0) {        // exact: has_pos <=> row_sum > 0
        per += -logf(p / (p + n));
        cnt += 1.f;
      }
    }
    #pragma unroll
    for (int o = 32; o >= 1; o >>= 1) {
      per += __shfl_xor(per, o);
      cnt += __shfl_xor(cnt, o);
    }
    if ((tid & 63) == 0) { s_p[tid >> 6] = per; s_c[tid >> 6] = cnt; }
    __syncthreads();
    if (tid == 0) {
      float P = s_p[0] + s_p[1] + s_p[2] + s_p[3];
      float C = s_c[0] + s_c[1] + s_c[2] + s_c[3];
      out[0] = P / fmaxf(C, 1.0f);
    }
  }
}

extern "C" void kernel_launch(void* const* d_in, const int* in_sizes, int n_in,
                              void* d_out, int out_size, void* d_ws, size_t ws_size,
                              hipStream_t stream) {
  const float* feat = (const float*)d_in[0];
  const float* labels = (const float*)d_in[1];
  float* out = (float*)d_out;
  char* ws = (char*)d_ws;
  // workspace (~1.2 MB):
  uint4* cf = (uint4*)(ws + 0);               // 1 MB swizzled bf16 view0
  uint4* Lbm = (uint4*)(ws + 1048576);        // 64 KB label masks
  int* rsv = (int*)(ws + 1114112);            // 16 KB row sums
  float* seedRaw = (float*)(ws + 1130496);    // 16 KB diag seeds
  float2* rowAcc = (float2*)(ws + 1146880);   // 32 KB per-row (p,n)
  unsigned* counter = (unsigned*)(ws + 1146880 + 32768);  // 4 B

  hipLaunchKernelGGL(prep_kernel, dim3(1024), dim3(256), 0, stream,
                     feat, labels, cf, Lbm, rsv, seedRaw, rowAcc, counter);
  hipLaunchKernelGGL(main_kernel, dim3(NTRI), dim3(256), 0, stream,
                     cf, Lbm, rsv, seedRaw, rowAcc, counter, out);
}

// Round 4
// 83.538 us; speedup vs baseline: 1.0071x; 1.0071x over previous
//
#include <hip/hip_runtime.h>
#include <math.h>

#define B_ROWS 4096
#define LBL 100
#define NCT 32     // 32x32 tile grid, upper triangle only
#define NTRI 528   // 32*33/2 tiles
#define NBLK 176   // blocks; 176*3 = 528 -> ONE dispatch round even at 1 blk/CU
#define TPB 3      // tiles per block

typedef __attribute__((ext_vector_type(8))) short bf16x8;
typedef __attribute__((ext_vector_type(4))) float f32x4;

__device__ __forceinline__ unsigned f2bf(float x) {
  union { float f; unsigned u; } a; a.f = x;
  unsigned r = a.u + 0x7fffu + ((a.u >> 16) & 1u);  // RNE
  return r >> 16;
}
__device__ __forceinline__ float bf2f(unsigned h) {
  return __uint_as_float(h << 16);
}

// Fused prep: one wave per row. Writes cf (bf16 view0, XOR-swizzled chunks:
// chunk(r,kc) of tile t at cf[t*2048 + kc*128 + ((r&127)^kc)]), 128-bit label
// masks, row sums, seedRaw = sum(bf16(f)^2) - 0.15 (lower bound on the raw
// diag MFMA dot; single source -> bit-identical for all consumers).
// Also zeroes rowAcc (its own row) and the finalize counter.
__global__ void prep_kernel(const float* __restrict__ feat,
                            const float* __restrict__ labels,
                            uint4* __restrict__ cf,
                            uint4* __restrict__ Lb,
                            int* __restrict__ rsv,
                            float* __restrict__ seedRaw,
                            float2* __restrict__ rowAcc,
                            unsigned* __restrict__ counter) {
  if (blockIdx.x == 0 && threadIdx.x == 0) *counter = 0u;
  int w = blockIdx.x * 4 + (threadIdx.x >> 6);
  int lane = threadIdx.x & 63;
  float2 f = ((const float2*)(feat + (size_t)w * 256))[lane];  // view0 row
  unsigned u0 = f2bf(f.x), u1 = f2bf(f.y);
  unsigned myu = u0 | (u1 << 16);
  float b0 = bf2f(u0), b1 = bf2f(u1);
  float s = b0 * b0 + b1 * b1;
  #pragma unroll
  for (int o = 32; o >= 1; o >>= 1) s += __shfl_xor(s, o);
  float x0 = labels[(size_t)w * LBL + lane];
  float x1 = (lane < LBL - 64) ? labels[(size_t)w * LBL + 64 + lane] : 0.0f;
  unsigned long long m0 = __ballot(x0 != 0.0f);
  unsigned long long m1 = __ballot(x1 != 0.0f);
  // pack: lane kc<16 gathers its chunk's 4 dwords from lanes kc*4+j
  int kc = lane & 15;
  unsigned q0 = __shfl(myu, kc * 4 + 0);
  unsigned q1 = __shfl(myu, kc * 4 + 1);
  unsigned q2 = __shfl(myu, kc * 4 + 2);
  unsigned q3 = __shfl(myu, kc * 4 + 3);
  if (lane < 16)
    cf[(size_t)(w >> 7) * 2048 + kc * 128 + ((w & 127) ^ kc)] =
        make_uint4(q0, q1, q2, q3);
  if (lane == 0) {
    Lb[w] = make_uint4((unsigned)m0, (unsigned)(m0 >> 32),
                       (unsigned)m1, (unsigned)(m1 >> 32));
    rsv[w] = __popcll(m0) + __popcll(m1);
    seedRaw[w] = s - 0.15f;  // 0.15 raw = 2.1 logit slack >> 1e-3 reassoc err
    rowAcc[w] = make_float2(0.0f, 0.0f);
  }
}

// 176 blocks x 3 upper-triangle 128x128 tiles each (tile ids b, b+176, b+352)
// -> ONE dispatch round at 1 block/CU; per-block fixed cold-latency cost is
// paid once, not 3x (rounds were the invariant ~31 us across r0/r2/r3).
// Per tile: MFMA fragments load straight from pre-swizzled cf; the K-loop's
// double-buffer regs (af2/bfr2) prefetch the NEXT tile's first chunk at the
// last K-step, so cross-tile latency hides under the epilogue; metadata loads
// issue before the MFMA loop so their latency hides under it. No barriers
// until the tail. Raw dots; *invT in epilogue; logits_max cancels in
// -log(p/(p+n)); terms below ref-6.3 raw underflow to 0 in the reference too.
// Sparse partials atomicAdd into rowAcc (coherent-point RMWs); ordering via
// wave-local vmcnt(0) drain + barrier + counter RMW (NO threadfence — the
// buffer_wbl2 storm was the round-1 regression). Last block finalizes.
__launch_bounds__(256, 1)
__global__ void main_kernel(const uint4* __restrict__ cf,
                            const uint4* __restrict__ Lb,
                            const int* __restrict__ rsv,
                            const float* __restrict__ seedRaw,
                            float2* __restrict__ rowAcc,
                            unsigned* __restrict__ counter,
                            float* __restrict__ out) {
  __shared__ unsigned s_done;
  __shared__ float s_p[4], s_c[4];

  const int tid = threadIdx.x;
  const int lane = tid & 63;
  const int l15 = lane & 15;
  const int quad = lane >> 4;
  const int wave = tid >> 6;
  const int wi = (wave & 1) * 64;   // wave row offset in 128
  const int wj = (wave >> 1) * 64;  // wave col offset in 128
  const float invT = 1.0f / 0.07f;

  // triangular decode for all 3 tiles up front (compile-time indexed after
  // unroll -> stays in registers)
  int bxA[TPB], byA[TPB];
  #pragma unroll
  for (int tt = 0; tt < TPB; ++tt) {
    int bid = blockIdx.x + tt * NBLK;
    int bx = 0, off = 0;
    while (bid >= off + (NCT - bx)) { off += NCT - bx; ++bx; }
    bxA[tt] = bx;
    byA[tt] = bx + (bid - off);
  }

  bf16x8 af[4], bfr[4], af2[4], bfr2[4];
  // prologue: tile 0, first K-chunk (kc = quad)
  {
    const uint4* Ab = cf + (size_t)bxA[0] * 2048;
    const uint4* Bb = cf + (size_t)byA[0] * 2048;
    const int kc = quad;
    #pragma unroll
    for (int t = 0; t < 4; ++t) {
      af[t]  = *(const bf16x8*)&Ab[kc * 128 + ((wi + t * 16 + l15) ^ kc)];
      bfr[t] = *(const bf16x8*)&Bb[kc * 128 + ((wj + t * 16 + l15) ^ kc)];
    }
  }

  #pragma unroll
  for (int tt = 0; tt < TPB; ++tt) {
    const int bx = bxA[tt], by = byA[tt];
    const bool diag = (bx == by);
    const int rowBase = bx * 128;
    const int colBase = by * 128;
    const uint4* Ab = cf + (size_t)bx * 2048;
    const uint4* Bb = cf + (size_t)by * 2048;

    // per-tile metadata issued BEFORE the MFMA loop (latency hides under it)
    uint4 clb[4];
    int crs[4];
    float scol[4], srow[16];
    #pragma unroll
    for (int tj = 0; tj < 4; ++tj) {
      int gcol = colBase + wj + tj * 16 + l15;
      clb[tj] = Lb[gcol];
      crs[tj] = rsv[gcol];
      scol[tj] = seedRaw[gcol];
    }
    #pragma unroll
    for (int ti = 0; ti < 4; ++ti) {
      float4 s4 = *(const float4*)&seedRaw[rowBase + wi + ti * 16 + quad * 4];
      srow[ti * 4 + 0] = s4.x; srow[ti * 4 + 1] = s4.y;
      srow[ti * 4 + 2] = s4.z; srow[ti * 4 + 3] = s4.w;
    }

    f32x4 acc[4][4];
    #pragma unroll
    for (int ti = 0; ti < 4; ++ti)
      #pragma unroll
      for (int tj = 0; tj < 4; ++tj)
        acc[ti][tj] = (f32x4){0.f, 0.f, 0.f, 0.f};

    // K loop; dbuf regs carry (a) this tile's next chunk for ks<3, (b) the
    // NEXT tile's first chunk at ks==3 (cross-tile prefetch under epilogue)
    #pragma unroll
    for (int ks = 0; ks < 4; ++ks) {
      if (ks < 3) {
        const int kc = (ks + 1) * 4 + quad;
        #pragma unroll
        for (int t = 0; t < 4; ++t) {
          af2[t]  = *(const bf16x8*)&Ab[kc * 128 + ((wi + t * 16 + l15) ^ kc)];
          bfr2[t] = *(const bf16x8*)&Bb[kc * 128 + ((wj + t * 16 + l15) ^ kc)];
        }
      } else if (tt < TPB - 1) {
        const uint4* An = cf + (size_t)bxA[tt + 1] * 2048;
        const uint4* Bn = cf + (size_t)byA[tt + 1] * 2048;
        const int kc = quad;
        #pragma unroll
        for (int t = 0; t < 4; ++t) {
          af2[t]  = *(const bf16x8*)&An[kc * 128 + ((wi + t * 16 + l15) ^ kc)];
          bfr2[t] = *(const bf16x8*)&Bn[kc * 128 + ((wj + t * 16 + l15) ^ kc)];
        }
      }
      #pragma unroll
      for (int ti = 0; ti < 4; ++ti)
        #pragma unroll
        for (int tj = 0; tj < 4; ++tj)
          acc[ti][tj] = __builtin_amdgcn_mfma_f32_16x16x32_bf16(
              af[ti], bfr[tj], acc[ti][tj], 0, 0, 0);
      if (ks < 3 || tt < TPB - 1) {
        #pragma unroll
        for (int t = 0; t < 4; ++t) { af[t] = af2[t]; bfr[t] = bfr2[t]; }
      }
    }

    // epilogue: C[row][col], row=wi+ti*16+quad*4+r, col=wj+tj*16+l15
    float p_s[16], n_s[16], cp[4], cn[4], cmax[4];
    #pragma unroll
    for (int i = 0; i < 16; ++i) { p_s[i] = 0.f; n_s[i] = 0.f; }
    #pragma unroll
    for (int tj = 0; tj < 4; ++tj) { cp[tj] = 0.f; cn[tj] = 0.f; cmax[tj] = -1e30f; }

    #pragma unroll
    for (int ti = 0; ti < 4; ++ti)
      #pragma unroll
      for (int r = 0; r < 4; ++r) {
        int si = ti * 4 + r;
        float l0 = acc[ti][0][r], l1 = acc[ti][1][r];
        float l2 = acc[ti][2][r], l3 = acc[ti][3][r];
        cmax[0] = fmaxf(cmax[0], l0);
        cmax[1] = fmaxf(cmax[1], l1);
        cmax[2] = fmaxf(cmax[2], l2);
        cmax[3] = fmaxf(cmax[3], l3);
        float tm = fmaxf(fmaxf(l0, l1), fmaxf(l2, l3));
        if (tm > srow[si] - 6.3f) {  // row-side slow path (~diag tiles only)
          int grow = rowBase + wi + ti * 16 + quad * 4 + r;
          uint4 la = Lb[grow];     // scattered but rare + L2-hot
          int ra = rsv[grow];
          float p = p_s[si], n = n_s[si];
          float lv[4] = {l0, l1, l2, l3};
          #pragma unroll
          for (int tj = 0; tj < 4; ++tj) {
            float e = __expf((lv[tj] - srow[si]) * invT);
            int inter = __popc(la.x & clb[tj].x) + __popc(la.y & clb[tj].y) +
                        __popc(la.z & clb[tj].z) + __popc(la.w & clb[tj].w);
            if (3 * inter > ra + crs[tj]) p += e; else n += e;  // sim>=0.5 exact
          }
          p_s[si] = p;
          n_s[si] = n;
        }
      }

    // col-side (transpose contribution) — off-diagonal tiles, ~never fires
    if (!diag) {
      #pragma unroll
      for (int tj = 0; tj < 4; ++tj) {
        if (cmax[tj] > scol[tj] - 6.3f) {
          float p = cp[tj], n = cn[tj];
          #pragma unroll
          for (int ti = 0; ti < 4; ++ti)
            #pragma unroll
            for (int r = 0; r < 4; ++r) {
              float e = __expf((acc[ti][tj][r] - scol[tj]) * invT);
              int grow = rowBase + wi + ti * 16 + quad * 4 + r;
              uint4 la = Lb[grow];
              int inter = __popc(la.x & clb[tj].x) + __popc(la.y & clb[tj].y) +
                          __popc(la.z & clb[tj].z) + __popc(la.w & clb[tj].w);
              if (3 * inter > rsv[grow] + crs[tj]) p += e; else n += e;
            }
          cp[tj] = p;
          cn[tj] = n;
        }
      }
    }

    // row-side: sum across the 16 lanes (same quad) sharing each row; lane 0
    // of each quad owns the row; atomics SKIPPED when zero (sparse)
    #pragma unroll
    for (int si = 0; si < 16; ++si) {
      float p = p_s[si], n = n_s[si];
      #pragma unroll
      for (int o = 8; o >= 1; o >>= 1) {
        p += __shfl_xor(p, o);
        n += __shfl_xor(n, o);
      }
      p_s[si] = p;
      n_s[si] = n;
    }
    if (l15 == 0) {
      #pragma unroll
      for (int ti = 0; ti < 4; ++ti)
        #pragma unroll
        for (int r = 0; r < 4; ++r) {
          float p = p_s[ti * 4 + r], n = n_s[ti * 4 + r];
          if (p != 0.f || n != 0.f) {
            int row = rowBase + wi + ti * 16 + quad * 4 + r;
            atomicAdd(&rowAcc[row].x, p);
            atomicAdd(&rowAcc[row].y, n);
          }
        }
    }
    // col-side: sum across the 4 quads sharing each column; skipped when zero
    #pragma unroll
    for (int tj = 0; tj < 4; ++tj) {
      float p = cp[tj], n = cn[tj];
      p += __shfl_xor(p, 16); n += __shfl_xor(n, 16);
      p += __shfl_xor(p, 32); n += __shfl_xor(n, 32);
      cp[tj] = p;
      cn[tj] = n;
    }
    if (!diag && quad == 0) {
      #pragma unroll
      for (int tj = 0; tj < 4; ++tj) {
        if (cp[tj] != 0.f || cn[tj] != 0.f) {
          int col = colBase + wj + tj * 16 + l15;
          atomicAdd(&rowAcc[col].x, cp[tj]);
          atomicAdd(&rowAcc[col].y, cn[tj]);
        }
      }
    }
  }  // tile loop

  // finalize tail — NO __threadfence (no L2 writeback). Drain this wave's
  // outstanding coherent-point RMWs, barrier so all 4 waves are drained,
  // then one counter RMW. Completion of an atomic == performed device-wide.
  asm volatile("s_waitcnt vmcnt(0)" ::: "memory");
  __syncthreads();
  if (tid == 0) s_done = atomicAdd(counter, 1u);
  __syncthreads();
  if (s_done == NBLK - 1) {  // last block: all rowAcc adds are globally done
    float per = 0.f, cnt = 0.f;
    #pragma unroll
    for (int it = 0; it < B_ROWS / 256; ++it) {
      int row = it * 256 + tid;
      unsigned long long u = __hip_atomic_load(
          (const unsigned long long*)&rowAcc[row], __ATOMIC_RELAXED,
          __HIP_MEMORY_SCOPE_AGENT);           // cache-bypassing coherent read
      float p = __uint_as_float((unsigned)u);
      float n = __uint_as_float((unsigned)(u >> 32));
      if (rsv[row] > 0) {        // exact: has_pos <=> row_sum > 0
        per += -logf(p / (p + n));
        cnt += 1.f;
      }
    }
    #pragma unroll
    for (int o = 32; o >= 1; o >>= 1) {
      per += __shfl_xor(per, o);
      cnt += __shfl_xor(cnt, o);
    }
    if ((tid & 63) == 0) { s_p[tid >> 6] = per; s_c[tid >> 6] = cnt; }
    __syncthreads();
    if (tid == 0) {
      float P = s_p[0] + s_p[1] + s_p[2] + s_p[3];
      float C = s_c[0] + s_c[1] + s_c[2] + s_c[3];
      out[0] = P / fmaxf(C, 1.0f);
    }
  }
}

extern "C" void kernel_launch(void* const* d_in, const int* in_sizes, int n_in,
                              void* d_out, int out_size, void* d_ws, size_t ws_size,
                              hipStream_t stream) {
  const float* feat = (const float*)d_in[0];
  const float* labels = (const float*)d_in[1];
  float* out = (float*)d_out;
  char* ws = (char*)d_ws;
  // workspace (~1.2 MB):
  uint4* cf = (uint4*)(ws + 0);               // 1 MB swizzled bf16 view0
  uint4* Lbm = (uint4*)(ws + 1048576);        // 64 KB label masks
  int* rsv = (int*)(ws + 1114112);            // 16 KB row sums
  float* seedRaw = (float*)(ws + 1130496);    // 16 KB diag seeds
  float2* rowAcc = (float2*)(ws + 1146880);   // 32 KB per-row (p,n)
  unsigned* counter = (unsigned*)(ws + 1146880 + 32768);  // 4 B

  hipLaunchKernelGGL(prep_kernel, dim3(1024), dim3(256), 0, stream,
                     feat, labels, cf, Lbm, rsv, seedRaw, rowAcc, counter);
  hipLaunchKernelGGL(main_kernel, dim3(NBLK), dim3(256), 0, stream,
                     cf, Lbm, rsv, seedRaw, rowAcc, counter, out);
}